// Round 1
// baseline (229.139 us; speedup 1.0000x reference)
//
#include <hip/hip_runtime.h>
#include <math.h>

#define N_TOK 16384
#define DM    4096
#define DH    2048
#define NE    64
#define TB    64
#define KT    32
#define TOPK  4

// out layout (all float32): topk_i [N,4] | topk_s [N,4] | scores [N,64] | aux_loss [1]
#define OFF_TI  0
#define OFF_TS  (N_TOK * TOPK)
#define OFF_SC  (N_TOK * TOPK * 2)
#define OFF_AUX (N_TOK * TOPK * 2 + N_TOK * NE)

__global__ __launch_bounds__(256) void torus_main(
    const float* __restrict__ u, const float* __restrict__ Ex,
    const float* __restrict__ Ey, const float* __restrict__ bias,
    const float* __restrict__ cp, const float* __restrict__ dp,
    const float* __restrict__ a1p, const float* __restrict__ b1p,
    float* __restrict__ out, float* __restrict__ esum)
{
    __shared__ float As[KT][68];        // k-major A tile, padded pitch
    __shared__ float Bs[KT][NE];        // matches E row-major layout exactly
    __shared__ float stile[TB][NE + 1]; // scores tile, +1 pad
    __shared__ float s_m[TB], s_inv[TB];

    const int tid = threadIdx.x;
    const int t0  = blockIdx.x * TB;
    const int ty  = tid >> 4;   // 0..15 -> token group
    const int tx  = tid & 15;   // 0..15 -> expert group

    float accx[4][4] = {{0.f}};
    float accy[4][4] = {{0.f}};

    const int row0 = tid >> 3;  // 0..31 (A staging row)
    const int c4   = tid & 7;   // 0..7  (A staging float4 column)

    auto run_half = [&](const float* __restrict__ Emat,
                        const float* __restrict__ uh,
                        float (&acc)[4][4]) {
        const float* ap0 = uh + (size_t)(t0 + row0) * DM + c4 * 4;
        const float* ap1 = uh + (size_t)(t0 + row0 + 32) * DM + c4 * 4;
        // prologue: chunk 0 into registers
        float4 a0 = *(const float4*)(ap0);
        float4 a1 = *(const float4*)(ap1);
        float4 b0 = *(const float4*)(Emat + (size_t)tid * 4);
        float4 b1 = *(const float4*)(Emat + (size_t)(tid + 256) * 4);
        for (int kc = 0; kc < DH; kc += KT) {
            __syncthreads();  // previous chunk's compute done
            As[c4 * 4 + 0][row0] = a0.x; As[c4 * 4 + 1][row0] = a0.y;
            As[c4 * 4 + 2][row0] = a0.z; As[c4 * 4 + 3][row0] = a0.w;
            As[c4 * 4 + 0][row0 + 32] = a1.x; As[c4 * 4 + 1][row0 + 32] = a1.y;
            As[c4 * 4 + 2][row0 + 32] = a1.z; As[c4 * 4 + 3][row0 + 32] = a1.w;
            *((float4*)&Bs[0][0] + tid)       = b0;
            *((float4*)&Bs[0][0] + tid + 256) = b1;
            __syncthreads();  // tile published
            const int kn = kc + KT;
            if (kn < DH) {    // issue next-chunk loads; latency hides under compute
                a0 = *(const float4*)(ap0 + kn);
                a1 = *(const float4*)(ap1 + kn);
                b0 = *(const float4*)(Emat + (size_t)kn * NE + tid * 4);
                b1 = *(const float4*)(Emat + (size_t)kn * NE + (tid + 256) * 4);
            }
            #pragma unroll
            for (int kk = 0; kk < KT; ++kk) {
                float4 av = *(const float4*)&As[kk][ty * 4];
                float4 bv = *(const float4*)&Bs[kk][tx * 4];
                float a_[4] = {av.x, av.y, av.z, av.w};
                float b_[4] = {bv.x, bv.y, bv.z, bv.w};
                #pragma unroll
                for (int i = 0; i < 4; ++i)
                    #pragma unroll
                    for (int j = 0; j < 4; ++j)
                        acc[i][j] = fmaf(a_[i], b_[j], acc[i][j]);
            }
        }
    };

    run_half(Ex, u, accx);
    run_half(Ey, u + DH, accy);

    const float c_  = *cp;
    const float d_  = *dp;
    const float a1_ = *a1p;
    const float b1_ = *b1p;

    #pragma unroll
    for (int i = 0; i < 4; ++i) {
        #pragma unroll
        for (int j = 0; j < 4; ++j) {
            float x  = tanhf(accx[i][j]) * 2.0f;
            float y  = tanhf(accy[i][j]) * 2.0f;
            float xa = fabsf(x), ya = fabsf(y);
            float s  = (powf(xa, a1_) + powf(ya, b1_)) *
                       expf(-(powf(xa, c_) + powf(ya, d_))) + bias[tx * 4 + j];
            stile[ty * 4 + i][tx * 4 + j] = s;
        }
    }
    __syncthreads();

    // per-token top-4 + softmax denom (threads 0..63, one token each)
    if (tid < TB) {
        const int t = tid;
        float bv[TOPK]; int bi[TOPK];
        #pragma unroll
        for (int p = 0; p < TOPK; ++p) {
            float best = -INFINITY; int besti = 0;
            for (int e = 0; e < NE; ++e) {
                float v = stile[t][e];
                bool taken = false;
                #pragma unroll
                for (int q = 0; q < p; ++q) taken = taken || (bi[q] == e);
                if (!taken && v > best) { best = v; besti = e; }  // strict > == lax.top_k tie-break
            }
            bv[p] = best; bi[p] = besti;
        }
        const float m = bv[0];
        float denom = 0.0f;
        for (int e = 0; e < NE; ++e) denom += expf(stile[t][e] - m);
        const float inv = 1.0f / denom;
        s_m[t] = m; s_inv[t] = inv;
        #pragma unroll
        for (int p = 0; p < TOPK; ++p) {
            out[OFF_TI + (size_t)(t0 + t) * TOPK + p] = (float)bi[p];
            out[OFF_TS + (size_t)(t0 + t) * TOPK + p] = bv[p];
        }
    }
    __syncthreads();

    // per-expert prob column-sums over this block's 64 tokens -> global accumulate
    if (tid < NE) {
        const int e = tid;
        float cs = 0.0f;
        for (int t = 0; t < TB; ++t)
            cs += expf(stile[t][e] - s_m[t]) * s_inv[t];
        atomicAdd(&esum[e], cs);
    }

    // scores tile -> global, coalesced
    for (int idx = tid; idx < TB * NE; idx += 256) {
        out[OFF_SC + (size_t)t0 * NE + idx] = stile[idx >> 6][idx & (NE - 1)];
    }
}

__global__ __launch_bounds__(64) void torus_aux(const float* __restrict__ esum,
                                                float* __restrict__ out)
{
    const int e = threadIdx.x;
    float s = esum[e] * (1.0f / (float)N_TOK);  // mean prob per expert
    float v = s * s;
    #pragma unroll
    for (int off = 32; off > 0; off >>= 1) v += __shfl_down(v, off);
    if (e == 0) out[OFF_AUX] = v * (float)NE;
}

extern "C" void kernel_launch(void* const* d_in, const int* in_sizes, int n_in,
                              void* d_out, int out_size, void* d_ws, size_t ws_size,
                              hipStream_t stream) {
    const float* u    = (const float*)d_in[0];
    const float* Ex   = (const float*)d_in[1];
    const float* Ey   = (const float*)d_in[2];
    const float* bias = (const float*)d_in[3];
    const float* cp   = (const float*)d_in[4];
    const float* dp   = (const float*)d_in[5];
    const float* a1p  = (const float*)d_in[6];
    const float* b1p  = (const float*)d_in[7];
    float* out  = (float*)d_out;
    float* esum = (float*)d_ws;

    hipMemsetAsync(esum, 0, NE * sizeof(float), stream);
    torus_main<<<N_TOK / TB, 256, 0, stream>>>(u, Ex, Ey, bias, cp, dp, a1p, b1p, out, esum);
    torus_aux<<<1, 64, 0, stream>>>(esum, out);
}

// Round 2
// 139.413 us; speedup vs baseline: 1.6436x; 1.6436x over previous
//
#include <hip/hip_runtime.h>
#include <math.h>

#define N_TOK 16384
#define DM    4096
#define DH    2048
#define NE    64
#define TB    64
#define TOPK  4
#define KQ    1024      // k-range per wave within its half
#define NSTEP 32        // KQ / 32

// out layout (all float32): topk_i [N,4] | topk_s [N,4] | scores [N,64] | aux_loss [1]
#define OFF_TI  0
#define OFF_TS  (N_TOK * TOPK)
#define OFF_SC  (N_TOK * TOPK * 2)
#define OFF_AUX (N_TOK * TOPK * 2 + N_TOK * NE)

typedef __attribute__((ext_vector_type(4))) float  f32x4;
typedef __attribute__((ext_vector_type(8))) __bf16 bf16x8;

// ws layout: __bf16 Bsplit[2 halves][3 splits][64 e][2048 k] (1.5 MB), then float esum[64]
#define BSPLIT_ELEMS (2 * 3 * NE * DH)

__device__ __forceinline__ void split3(float a, __bf16& h, __bf16& m, __bf16& l) {
    h = (__bf16)a;                 // RNE; a = h+m+l is an EXACT decomposition (24 = 8+8+8 bits)
    float r = a - (float)h;        // exact (Sterbenz)
    m = (__bf16)r;
    float r2 = r - (float)m;       // exact
    l = (__bf16)r2;                // exact (<=8 significant bits left)
}

// Pre-split + transpose E into ws: Bws[(half*3+s)*64 + e][k] bf16, k contiguous.
__global__ __launch_bounds__(256) void prep_B(
    const float* __restrict__ Ex, const float* __restrict__ Ey,
    __bf16* __restrict__ Bws)
{
    __shared__ float te[128][68];
    const int tid  = threadIdx.x;
    const int half = blockIdx.x >> 4;
    const int k0   = (blockIdx.x & 15) * 128;
    const float* E = half ? Ey : Ex;
    #pragma unroll
    for (int i = 0; i < 8; ++i) {                    // 128x64 fp32 tile, coalesced
        int idx = tid + 256 * i;                     // float4 index
        int row = idx >> 4, c4 = idx & 15;
        f32x4 v = *(const f32x4*)(E + (size_t)(k0 + row) * NE + c4 * 4);
        *(f32x4*)&te[row][c4 * 4] = v;
    }
    __syncthreads();
    const int e  = tid >> 2;
    const int kl = (tid & 3) * 32;
    bf16x8 vh[4], vm[4], vl[4];
    #pragma unroll
    for (int g = 0; g < 4; ++g)
        #pragma unroll
        for (int j = 0; j < 8; ++j) {
            __bf16 h, m, l;
            split3(te[kl + g * 8 + j][e], h, m, l);
            vh[g][j] = h; vm[g][j] = m; vl[g][j] = l;
        }
    size_t base = ((size_t)(half * 3) * NE + e) * DH + k0 + kl;
    #pragma unroll
    for (int g = 0; g < 4; ++g) {
        *(bf16x8*)(Bws + base                        + g * 8) = vh[g];
        *(bf16x8*)(Bws + base + (size_t)NE * DH      + g * 8) = vm[g];
        *(bf16x8*)(Bws + base + (size_t)2 * NE * DH  + g * 8) = vl[g];
    }
}

__global__ __launch_bounds__(256, 1) void torus_mfma(
    const float* __restrict__ u, const __bf16* __restrict__ Bws,
    const float* __restrict__ bias,
    const float* __restrict__ cp, const float* __restrict__ dp,
    const float* __restrict__ a1p, const float* __restrict__ b1p,
    float* __restrict__ out, float* __restrict__ esum)
{
    __shared__ float pre[4][NE][68];      // per-wave partial pre-activations, [e][t]
    __shared__ float stile[TB][NE + 1];
    __shared__ float s_m[TB], s_inv[TB];

    const int tid  = threadIdx.x;
    const int t0   = blockIdx.x * TB;
    const int lane = tid & 63;
    const int wv   = tid >> 6;
    const int half = wv >> 1;             // 0: x-half, 1: y-half
    const int kq   = wv & 1;              // k-quarter within half
    const int lr   = lane & 15;           // MFMA row (A) / col (B)
    const int lk   = (lane >> 4) * 8;     // k sub-offset within a 32-step

    // per-lane element offsets (32-bit), SGPR base + VGPR offset addressing
    unsigned abo[4];
    #pragma unroll
    for (int rt = 0; rt < 4; ++rt)
        abo[rt] = (unsigned)((t0 + rt * 16 + lr) * DM + half * DH + kq * KQ + lk);
    unsigned bbo[3][4];
    #pragma unroll
    for (int s = 0; s < 3; ++s)
        #pragma unroll
        for (int et = 0; et < 4; ++et)
            bbo[s][et] = (unsigned)(((half * 3 + s) * NE + et * 16 + lr) * DH + kq * KQ + lk);

    f32x4 acc[4][4] = {};
    f32x4 raw[4][2];
    bf16x8 bh[4], bhN[4];
    #pragma unroll
    for (int rt = 0; rt < 4; ++rt) {
        raw[rt][0] = *(const f32x4*)(u + abo[rt]);
        raw[rt][1] = *(const f32x4*)(u + abo[rt] + 4);
    }
    #pragma unroll
    for (int et = 0; et < 4; ++et) bh[et] = *(const bf16x8*)(Bws + bbo[0][et]);

    for (int ks = 0; ks < NSTEP; ++ks) {
        // split current A step (raw -> h/m/l fragments), then raw is free for prefetch
        bf16x8 sh[4], sm[4], sl[4];
        #pragma unroll
        for (int rt = 0; rt < 4; ++rt)
            #pragma unroll
            for (int q = 0; q < 2; ++q)
                #pragma unroll
                for (int j = 0; j < 4; ++j) {
                    __bf16 h, m, l;
                    split3(raw[rt][q][j], h, m, l);
                    sh[rt][q * 4 + j] = h; sm[rt][q * 4 + j] = m; sl[rt][q * 4 + j] = l;
                }
        const int ksn = (ks < NSTEP - 1) ? ks + 1 : ks;   // clamp: no OOB on last step
        #pragma unroll
        for (int rt = 0; rt < 4; ++rt) {                  // prefetch next A (HBM, ~1 step lead)
            raw[rt][0] = *(const f32x4*)(u + abo[rt] + ksn * 32);
            raw[rt][1] = *(const f32x4*)(u + abo[rt] + ksn * 32 + 4);
        }
        bf16x8 bm[4], bl[4];
        #pragma unroll
        for (int et = 0; et < 4; ++et) {                  // B: L2-hit loads
            bm[et]  = *(const bf16x8*)(Bws + bbo[1][et] + ks * 32);
            bl[et]  = *(const bf16x8*)(Bws + bbo[2][et] + ks * 32);
            bhN[et] = *(const bf16x8*)(Bws + bbo[0][et] + ksn * 32);
        }
        // phase 1: all products against bh (latency cover for bm/bl)
        #pragma unroll
        for (int et = 0; et < 4; ++et)
            #pragma unroll
            for (int rt = 0; rt < 4; ++rt) {
                acc[rt][et] = __builtin_amdgcn_mfma_f32_16x16x32_bf16(sl[rt], bh[et], acc[rt][et], 0, 0, 0);
                acc[rt][et] = __builtin_amdgcn_mfma_f32_16x16x32_bf16(sm[rt], bh[et], acc[rt][et], 0, 0, 0);
                acc[rt][et] = __builtin_amdgcn_mfma_f32_16x16x32_bf16(sh[rt], bh[et], acc[rt][et], 0, 0, 0);
            }
        // phase 2: against bm
        #pragma unroll
        for (int et = 0; et < 4; ++et)
            #pragma unroll
            for (int rt = 0; rt < 4; ++rt) {
                acc[rt][et] = __builtin_amdgcn_mfma_f32_16x16x32_bf16(sm[rt], bm[et], acc[rt][et], 0, 0, 0);
                acc[rt][et] = __builtin_amdgcn_mfma_f32_16x16x32_bf16(sh[rt], bm[et], acc[rt][et], 0, 0, 0);
            }
        // phase 3: against bl
        #pragma unroll
        for (int et = 0; et < 4; ++et)
            #pragma unroll
            for (int rt = 0; rt < 4; ++rt)
                acc[rt][et] = __builtin_amdgcn_mfma_f32_16x16x32_bf16(sh[rt], bl[et], acc[rt][et], 0, 0, 0);
        #pragma unroll
        for (int et = 0; et < 4; ++et) bh[et] = bhN[et];
    }

    // ---- epilogue: combine wave partials, pointwise, topk, softmax ----
    __syncthreads();
    #pragma unroll
    for (int rt = 0; rt < 4; ++rt)
        #pragma unroll
        for (int et = 0; et < 4; ++et) {
            int e = et * 16 + lr;                       // D: col = lane&15
            int t = rt * 16 + ((lane >> 4) << 2);       // D: row = (lane>>4)*4 + reg
            *(f32x4*)&pre[wv][e][t] = acc[rt][et];
        }
    __syncthreads();

    {
        const float c_ = *cp, d_ = *dp, a1_ = *a1p, b1_ = *b1p;
        const int t  = tid >> 2;
        const int e0 = (tid & 3) * 16;
        #pragma unroll
        for (int i = 0; i < 16; ++i) {
            int e = e0 + i;
            float x = pre[0][e][t] + pre[1][e][t];
            float y = pre[2][e][t] + pre[3][e][t];
            x = tanhf(x) * 2.0f; y = tanhf(y) * 2.0f;
            float xa = fabsf(x), ya = fabsf(y);
            float sc = (powf(xa, a1_) + powf(ya, b1_)) *
                       expf(-(powf(xa, c_) + powf(ya, d_))) + bias[e];
            stile[t][e] = sc;
        }
    }
    __syncthreads();

    if (tid < TB) {
        const int t = tid;
        float bv[TOPK]; int bi[TOPK];
        #pragma unroll
        for (int p = 0; p < TOPK; ++p) {
            float best = -INFINITY; int besti = 0;
            for (int e = 0; e < NE; ++e) {
                float v = stile[t][e];
                bool taken = false;
                #pragma unroll
                for (int q = 0; q < p; ++q) taken = taken || (bi[q] == e);
                if (!taken && v > best) { best = v; besti = e; }  // strict > == lax.top_k tie-break
            }
            bv[p] = best; bi[p] = besti;
        }
        const float m = bv[0];
        float denom = 0.0f;
        for (int e = 0; e < NE; ++e) denom += expf(stile[t][e] - m);
        const float inv = 1.0f / denom;
        s_m[t] = m; s_inv[t] = inv;
        #pragma unroll
        for (int p = 0; p < TOPK; ++p) {
            out[OFF_TI + (size_t)(t0 + t) * TOPK + p] = (float)bi[p];
            out[OFF_TS + (size_t)(t0 + t) * TOPK + p] = bv[p];
        }
    }
    __syncthreads();

    if (tid < NE) {
        const int e = tid;
        float cs = 0.0f;
        for (int t = 0; t < TB; ++t)
            cs += expf(stile[t][e] - s_m[t]) * s_inv[t];
        atomicAdd(&esum[e], cs);
    }

    for (int idx = tid; idx < TB * NE; idx += 256)
        out[OFF_SC + (size_t)t0 * NE + idx] = stile[idx >> 6][idx & (NE - 1)];
}

__global__ __launch_bounds__(64) void torus_aux(const float* __restrict__ esum,
                                                float* __restrict__ out)
{
    const int e = threadIdx.x;
    float s = esum[e] * (1.0f / (float)N_TOK);
    float v = s * s;
    #pragma unroll
    for (int off = 32; off > 0; off >>= 1) v += __shfl_down(v, off);
    if (e == 0) out[OFF_AUX] = v * (float)NE;
}

extern "C" void kernel_launch(void* const* d_in, const int* in_sizes, int n_in,
                              void* d_out, int out_size, void* d_ws, size_t ws_size,
                              hipStream_t stream) {
    const float* u    = (const float*)d_in[0];
    const float* Ex   = (const float*)d_in[1];
    const float* Ey   = (const float*)d_in[2];
    const float* bias = (const float*)d_in[3];
    const float* cp   = (const float*)d_in[4];
    const float* dp   = (const float*)d_in[5];
    const float* a1p  = (const float*)d_in[6];
    const float* b1p  = (const float*)d_in[7];
    float* out = (float*)d_out;
    __bf16* Bws = (__bf16*)d_ws;
    float* esum = (float*)((char*)d_ws + (size_t)BSPLIT_ELEMS * sizeof(__bf16));

    prep_B<<<32, 256, 0, stream>>>(Ex, Ey, Bws);
    hipMemsetAsync(esum, 0, NE * sizeof(float), stream);
    torus_mfma<<<N_TOK / TB, 256, 0, stream>>>(u, Bws, bias, cp, dp, a1p, b1p, out, esum);
    torus_aux<<<1, 64, 0, stream>>>(esum, out);
}